// Round 9
// baseline (236.262 us; speedup 1.0000x reference)
//
#include <hip/hip_runtime.h>
#include <math.h>

#define D 128
#define EPS 1e-6f
#define TLD 72                 // shorts per row of sT/vT (144B rows)
#define TSZ (128 * TLD)        // 9216 shorts = 18432 B per buffer
#define SKR_LD 136             // retrieve kernel (unchanged, proven)

typedef __attribute__((ext_vector_type(8))) short short8;
typedef __attribute__((ext_vector_type(4))) float f32x4;
typedef unsigned short ushort_t;
typedef unsigned long long u64;

__device__ __forceinline__ float elu1(float x) {
    float e = __expf(fminf(x, 0.f));
    return x > 0.f ? x + 1.f : e;
}
__device__ __forceinline__ unsigned short bf16rne(float f) {
    unsigned u = __builtin_bit_cast(unsigned, f);
    u += 0x7FFFu + ((u >> 16) & 1u);
    return (unsigned short)(u >> 16);
}
__device__ __forceinline__ float bf2f(unsigned short h) {
    unsigned u = (unsigned)h << 16;
    return __builtin_bit_cast(float, u);
}
__device__ __forceinline__ u64 pack4(float a, float b, float c, float d) {
    return (u64)bf16rne(a) | ((u64)bf16rne(b) << 16) |
           ((u64)bf16rne(c) << 32) | ((u64)bf16rne(d) << 48);
}
// swizzled short-index of 16B unit u (0..7) within row f of a [128][TLD] tile.
// XOR with (f&7) AND ((f>>3)&7): the second term breaks the m<->m+8 bank
// alias of the A-frag read pattern (round-8 swizzle was still 4-way).
__device__ __forceinline__ int swz(int f, int u) {
    return TLD * f + 8 * (u ^ (f & 7) ^ ((f >> 3) & 7));
}

// ---------------------------------------------------------------------------
// Update (reformulated, round-8 dataflow): per (bh,chunk) accumulate
//   pP = sigma^T V,  pG = sigma^T diag(1/(sigma.z+eps)) sigma,  pz = sum sigma
// 64-row batches (halved barrier + norm overhead), packed 7-shfl/half norm
// reduce, one lgkm-only barrier per batch.  512 thr = 8 waves; wave w owns
// e/f-tile w.  VGPR budget: acc=64 AGPR + <=64 VGPR (128 cap at (512,4);
// round 5 showed exceeding it spills catastrophically).
// ---------------------------------------------------------------------------
__global__ __launch_bounds__(512, 4)
void k_update(const float* __restrict__ key, const float* __restrict__ value,
              const float* __restrict__ z,
              float* __restrict__ pP, float* __restrict__ pG,
              float* __restrict__ pz, int S)
{
    __shared__ alignas(16) ushort_t sT[2 * TSZ];   // sigma^T [128 d][64 s] bf16, dbuf
    __shared__ alignas(16) ushort_t vT[2 * TSZ];   // V^T     [128 e][64 s] bf16, dbuf
    __shared__ float nrm[2][64];                   // 1/(sigma.z+eps), dbuf

    const int t  = threadIdx.x;
    const int bh = blockIdx.x, ch = blockIdx.y, NCH = gridDim.y;
    const int SC = S / NCH, NB = SC / 64, s0g = ch * SC;

    const int w = t >> 6, g = (t >> 4) & 3, m = t & 15;  // compute roles
    const int c2 = t & 63;                               // stage lane (also l)

    const float* Kb = key   + (size_t)bh * S * D;
    const float* Vb = value + (size_t)bh * S * D;
    const float* zb = z + (size_t)bh * D;

    const float2 zr = *(const float2*)&zb[2 * c2];

    f32x4 accP[8], accG[8];
    #pragma unroll
    for (int dt = 0; dt < 8; ++dt) { accP[dt] = 0.f; accG[dt] = 0.f; }
    float zacc0 = 0.f, zacc1 = 0.f;

    // stage 64 rows: elu(K)->sT, V->vT (transposed+swizzled); per-half packed
    // norm reduce (3 merge shfl + 4 butterfly shfl); V loaded here (issued at
    // top, consumed at bottom — covered by the K-side chain).
    auto STAGE = [&](const float2* kr, int b, int buf) {
        float2 vr[8];
        #pragma unroll
        for (int h = 0; h < 2; ++h)
            #pragma unroll
            for (int i = 0; i < 4; ++i)
                vr[4 * h + i] = *(const float2*)&Vb[(size_t)(s0g + 64 * b + 32 * h + 4 * w + i) * D + 2 * c2];

        #pragma unroll
        for (int h = 0; h < 2; ++h) {
            float sv0[4], sv1[4], p4[4];
            #pragma unroll
            for (int i = 0; i < 4; ++i) {
                sv0[i] = elu1(kr[4 * h + i].x);
                sv1[i] = elu1(kr[4 * h + i].y);
            }
            const int u = 4 * h + (w >> 1), h4 = 4 * (w & 1);
            *(u64*)&sT[buf * TSZ + swz(2 * c2, u) + h4]     = pack4(sv0[0], sv0[1], sv0[2], sv0[3]);
            *(u64*)&sT[buf * TSZ + swz(2 * c2 + 1, u) + h4] = pack4(sv1[0], sv1[1], sv1[2], sv1[3]);
            #pragma unroll
            for (int i = 0; i < 4; ++i) {
                p4[i] = sv0[i] * zr.x + sv1[i] * zr.y;
                zacc0 += sv0[i]; zacc1 += sv1[i];
            }
            // packed reduce: merge 4 values -> 1 (value idx = c2&3), then tree
            float w2a, w2b, x;
            { float a = (c2 & 1) ? p4[1] : p4[0], b2 = (c2 & 1) ? p4[0] : p4[1];
              w2a = a + __shfl_xor(b2, 1, 64); }
            { float a = (c2 & 1) ? p4[3] : p4[2], b2 = (c2 & 1) ? p4[2] : p4[3];
              w2b = a + __shfl_xor(b2, 1, 64); }
            { float a = (c2 & 2) ? w2b : w2a, b2 = (c2 & 2) ? w2a : w2b;
              x = a + __shfl_xor(b2, 2, 64); }
            x += __shfl_xor(x, 4, 64);
            x += __shfl_xor(x, 8, 64);
            x += __shfl_xor(x, 16, 64);
            x += __shfl_xor(x, 32, 64);
            if (c2 < 4)
                nrm[buf][32 * h + 4 * w + c2] = 1.f / (x + EPS);
        }
        // V side (vmcnt wait lands here, covered by the chain above)
        #pragma unroll
        for (int h = 0; h < 2; ++h) {
            const int u = 4 * h + (w >> 1), h4 = 4 * (w & 1);
            *(u64*)&vT[buf * TSZ + swz(2 * c2, u) + h4] =
                pack4(vr[4 * h + 0].x, vr[4 * h + 1].x, vr[4 * h + 2].x, vr[4 * h + 3].x);
            *(u64*)&vT[buf * TSZ + swz(2 * c2 + 1, u) + h4] =
                pack4(vr[4 * h + 0].y, vr[4 * h + 1].y, vr[4 * h + 2].y, vr[4 * h + 3].y);
        }
    };

    // prologue: load+stage batch 0; prefetch K(1)
    float2 kr[8];
    #pragma unroll
    for (int h = 0; h < 2; ++h)
        #pragma unroll
        for (int i = 0; i < 4; ++i)
            kr[4 * h + i] = *(const float2*)&Kb[(size_t)(s0g + 32 * h + 4 * w + i) * D + 2 * c2];
    STAGE(kr, 0, 0);
    if (NB > 1) {
        #pragma unroll
        for (int h = 0; h < 2; ++h)
            #pragma unroll
            for (int i = 0; i < 4; ++i)
                kr[4 * h + i] = *(const float2*)&Kb[(size_t)(s0g + 64 + 32 * h + 4 * w + i) * D + 2 * c2];
    }
    __syncthreads();

    for (int b = 0; b < NB; ++b) {
        const int cur = b & 1;

        // ---- COMPUTE(b): 32 MFMAs; only one ks-slice of B-frags live ----
        #pragma unroll
        for (int ks = 0; ks < 2; ++ks) {
            short8 bv = *(short8*)&vT[cur * TSZ + swz(16 * w + m, 4 * ks + g)];
            short8 bs = *(short8*)&sT[cur * TSZ + swz(16 * w + m, 4 * ks + g)];
            short8 bg;
            #pragma unroll
            for (int j = 0; j < 8; ++j)
                bg[j] = (short)bf16rne(bf2f((unsigned short)bs[j]) * nrm[cur][32 * ks + 8 * g + j]);
            #pragma unroll
            for (int dt = 0; dt < 8; ++dt) {
                short8 a = *(short8*)&sT[cur * TSZ + swz(16 * dt + m, 4 * ks + g)];
                accP[dt] = __builtin_amdgcn_mfma_f32_16x16x32_bf16(a, bv, accP[dt], 0, 0, 0);
                accG[dt] = __builtin_amdgcn_mfma_f32_16x16x32_bf16(a, bg, accG[dt], 0, 0, 0);
            }
        }

        // ---- STAGE(b+1); then issue K loads for b+2 ----
        if (b + 1 < NB) {
            STAGE(kr, b + 1, cur ^ 1);
            if (b + 2 < NB) {
                const int snx = s0g + 64 * (b + 2);
                #pragma unroll
                for (int h = 0; h < 2; ++h)
                    #pragma unroll
                    for (int i = 0; i < 4; ++i)
                        kr[4 * h + i] = *(const float2*)&Kb[(size_t)(snx + 32 * h + 4 * w + i) * D + 2 * c2];
            }
        }
        // lgkm-only barrier: LDS drained, K prefetch stays in flight
        asm volatile("s_waitcnt lgkmcnt(0)\n\ts_barrier" ::: "memory");
    }

    // write partials (fp32)
    float* pPb = pP + ((size_t)bh * NCH + ch) * (D * D);
    float* pGb = pG + ((size_t)bh * NCH + ch) * (D * D);
    #pragma unroll
    for (int dt = 0; dt < 8; ++dt)
        #pragma unroll
        for (int r = 0; r < 4; ++r) {
            pPb[(size_t)(16 * dt + 4 * g + r) * D + 16 * w + m] = accP[dt][r];
            pGb[(size_t)(16 * dt + 4 * g + r) * D + 16 * w + m] = accG[dt][r];
        }

    // z partial: reduce 8 wave-row-groups via LDS aliased on sT
    __syncthreads();
    float* zsc = (float*)sT;   // [8][128]
    zsc[w * 128 + 2 * c2]     = zacc0;
    zsc[w * 128 + 2 * c2 + 1] = zacc1;
    __syncthreads();
    if (t < 128) {
        float a = 0.f;
        #pragma unroll
        for (int r = 0; r < 8; ++r) a += zsc[r * 128 + t];
        pz[((size_t)bh * NCH + ch) * D + t] = a;
    }
}

// ---------------------------------------------------------------------------
// Sum: Mtmp = M + sum_ch pP ; (gh,gl) = split-bf16 of -(sum_ch pG) ;
//      z_new = z + sum_ch pz
// ---------------------------------------------------------------------------
__global__ void k_sum(const float* __restrict__ M, const float* __restrict__ z,
                      const float* __restrict__ pP, const float* __restrict__ pG,
                      const float* __restrict__ pz,
                      float* __restrict__ Mtmp, ushort_t* __restrict__ gh,
                      ushort_t* __restrict__ gl, float* __restrict__ znew, int NCH)
{
    const int bh = blockIdx.x, sl = blockIdx.y, t = threadIdx.x;
    const size_t base = (size_t)bh * D * D;
    for (int i = sl * 2048 + t; i < (sl + 1) * 2048; i += 256) {
        float sp = M[base + i];
        float sg = 0.f;
        for (int c = 0; c < NCH; ++c) {
            sp += pP[((size_t)bh * NCH + c) * (D * D) + i];
            sg += pG[((size_t)bh * NCH + c) * (D * D) + i];
        }
        Mtmp[base + i] = sp;
        float nG = -sg;
        unsigned short hi = bf16rne(nG);
        gh[base + i] = hi;
        gl[base + i] = bf16rne(nG - bf2f(hi));
    }
    if (sl == 0 && t < D) {
        float a = z[(size_t)bh * D + t];
        for (int c = 0; c < NCH; ++c) a += pz[((size_t)bh * NCH + c) * D + t];
        znew[(size_t)bh * D + t] = a;
    }
}

// ---------------------------------------------------------------------------
// GM: M_new = Mtmp + (gh+gl) @ M   (gh/gl hold -G in split bf16)
// ---------------------------------------------------------------------------
__global__ __launch_bounds__(256)
void k_gm(const float* __restrict__ M, const float* __restrict__ Mtmp,
          const ushort_t* __restrict__ gh, const ushort_t* __restrict__ gl,
          float* __restrict__ Mnew)
{
    const int bh = blockIdx.x, t = threadIdx.x;
    const int w2 = t >> 6, g = (t >> 4) & 3, m = t & 15;
    const float* Mb = M + (size_t)bh * D * D;
    const float* Tb = Mtmp + (size_t)bh * D * D;
    const ushort_t* ghb = gh + (size_t)bh * D * D;
    const ushort_t* glb = gl + (size_t)bh * D * D;
    float* Ob = Mnew + (size_t)bh * D * D;

    f32x4 acc[8][2];
    #pragma unroll
    for (int dt = 0; dt < 8; ++dt)
        #pragma unroll
        for (int p = 0; p < 2; ++p)
            #pragma unroll
            for (int r = 0; r < 4; ++r)
                acc[dt][p][r] = Tb[(size_t)(16 * dt + 4 * g + r) * D + 32 * w2 + 16 * p + m];

    #pragma unroll
    for (int ks = 0; ks < 4; ++ks) {
        short8 bm[2];
        #pragma unroll
        for (int p = 0; p < 2; ++p)
            #pragma unroll
            for (int j = 0; j < 8; ++j)
                bm[p][j] = (short)bf16rne(Mb[(size_t)(32 * ks + 8 * g + j) * D + 32 * w2 + 16 * p + m]);
        #pragma unroll
        for (int dt = 0; dt < 8; ++dt) {
            short8 ah = *(const short8*)&ghb[(size_t)(16 * dt + m) * D + 32 * ks + 8 * g];
            short8 al = *(const short8*)&glb[(size_t)(16 * dt + m) * D + 32 * ks + 8 * g];
            #pragma unroll
            for (int p = 0; p < 2; ++p) {
                acc[dt][p] = __builtin_amdgcn_mfma_f32_16x16x32_bf16(ah, bm[p], acc[dt][p], 0, 0, 0);
                acc[dt][p] = __builtin_amdgcn_mfma_f32_16x16x32_bf16(al, bm[p], acc[dt][p], 0, 0, 0);
            }
        }
    }

    #pragma unroll
    for (int dt = 0; dt < 8; ++dt)
        #pragma unroll
        for (int p = 0; p < 2; ++p)
            #pragma unroll
            for (int r = 0; r < 4; ++r)
                Ob[(size_t)(16 * dt + 4 * g + r) * D + 32 * w2 + 16 * p + m] = acc[dt][p][r];
}

// ---------------------------------------------------------------------------
// Retrieve: out = (sigma_q @ M_new) / (sigma_q @ z_new + eps)
// (unchanged since round 2 — proven correct, at memory floor)
// ---------------------------------------------------------------------------
__global__ __launch_bounds__(256, 2)
void k_retrieve(const float* __restrict__ query, const float* __restrict__ Mnew,
                const float* __restrict__ znew, float* __restrict__ out, int S)
{
    __shared__ alignas(16) ushort_t sqR[2][32 * SKR_LD];
    __shared__ float normsh[2][32];

    const int t  = threadIdx.x;
    const int bh = blockIdx.x, ch = blockIdx.y, NCH = gridDim.y;
    const int SC = S / NCH;
    const int NB = SC / 32;
    const int s0g = ch * SC;

    const int w = t >> 6, g = (t >> 4) & 3, m = t & 15;
    const int sb = t >> 5, db = t & 31;

    const float* Qb = query + (size_t)bh * S * D;
    const float* Mb = Mnew + (size_t)bh * D * D;
    const float* zb = znew + (size_t)bh * D;
    float*       Ob = out + (size_t)bh * S * D;

    float zr[4];
    #pragma unroll
    for (int j = 0; j < 4; ++j) zr[j] = zb[4 * db + j];

    short8 Bf[4][2];
    #pragma unroll
    for (int ks = 0; ks < 4; ++ks)
        #pragma unroll
        for (int p = 0; p < 2; ++p) {
            short8 f;
            #pragma unroll
            for (int j = 0; j < 8; ++j)
                f[j] = (short)bf16rne(Mb[(size_t)(32 * ks + 8 * g + j) * D + 16 * (2 * w + p) + m]);
            Bf[ks][p] = f;
        }

    auto STAGE_PROC = [&](const float4* qreg, int bu) {
        float sv[4][4];
        #pragma unroll
        for (int js = 0; js < 4; ++js) {
            sv[js][0] = elu1(qreg[js].x); sv[js][1] = elu1(qreg[js].y);
            sv[js][2] = elu1(qreg[js].z); sv[js][3] = elu1(qreg[js].w);
        }
        #pragma unroll
        for (int js = 0; js < 4; ++js)
            *(u64*)&sqR[bu][(4 * sb + js) * SKR_LD + 4 * db] =
                pack4(sv[js][0], sv[js][1], sv[js][2], sv[js][3]);
        float np[4];
        #pragma unroll
        for (int js = 0; js < 4; ++js)
            np[js] = sv[js][0] * zr[0] + sv[js][1] * zr[1] +
                     sv[js][2] * zr[2] + sv[js][3] * zr[3];
        #pragma unroll
        for (int mask = 16; mask >= 1; mask >>= 1) {
            np[0] += __shfl_xor(np[0], mask, 64);
            np[1] += __shfl_xor(np[1], mask, 64);
            np[2] += __shfl_xor(np[2], mask, 64);
            np[3] += __shfl_xor(np[3], mask, 64);
        }
        if (db < 4) {
            float v = db == 0 ? np[0] : db == 1 ? np[1] : db == 2 ? np[2] : np[3];
            normsh[bu][4 * sb + db] = v + EPS;
        }
    };

    {
        float4 qreg[4];
        #pragma unroll
        for (int js = 0; js < 4; ++js)
            qreg[js] = *(const float4*)&Qb[(size_t)(s0g + 4 * sb + js) * D + 4 * db];
        STAGE_PROC(qreg, 0);
    }
    __syncthreads();

    for (int b = 0; b < NB; ++b) {
        const int bu = b & 1;
        float4 qreg[4];
        if (b + 1 < NB) {
            #pragma unroll
            for (int js = 0; js < 4; ++js)
                qreg[js] = *(const float4*)&Qb[(size_t)(s0g + 32 * (b + 1) + 4 * sb + js) * D + 4 * db];
        }

        f32x4 mp[2][2];
        #pragma unroll
        for (int st = 0; st < 2; ++st)
            #pragma unroll
            for (int p = 0; p < 2; ++p) mp[st][p] = 0.f;
        #pragma unroll
        for (int st = 0; st < 2; ++st)
            #pragma unroll
            for (int ks = 0; ks < 4; ++ks) {
                short8 a = *(short8*)&sqR[bu][(16 * st + m) * SKR_LD + 32 * ks + 8 * g];
                #pragma unroll
                for (int p = 0; p < 2; ++p)
                    mp[st][p] = __builtin_amdgcn_mfma_f32_16x16x32_bf16(a, Bf[ks][p], mp[st][p], 0, 0, 0);
            }

        #pragma unroll
        for (int st = 0; st < 2; ++st)
            #pragma unroll
            for (int r = 0; r < 4; ++r) {
                float rn = 1.f / normsh[bu][16 * st + 4 * g + r];
                #pragma unroll
                for (int p = 0; p < 2; ++p)
                    Ob[(size_t)(s0g + 32 * b + 16 * st + 4 * g + r) * D + 16 * (2 * w + p) + m] =
                        mp[st][p][r] * rn;
            }

        if (b + 1 < NB) STAGE_PROC(qreg, (b + 1) & 1);
        __syncthreads();
    }
}

// ---------------------------------------------------------------------------
extern "C" void kernel_launch(void* const* d_in, const int* in_sizes, int n_in,
                              void* d_out, int out_size, void* d_ws, size_t ws_size,
                              hipStream_t stream)
{
    const float* q = (const float*)d_in[0];
    const float* k = (const float*)d_in[1];
    const float* v = (const float*)d_in[2];
    const float* M = (const float*)d_in[3];
    const float* z = (const float*)d_in[4];

    const int BH = in_sizes[3] / (D * D);
    const int S  = in_sizes[0] / (BH * D);
    const int NCH = 8;

    float* out  = (float*)d_out;
    float* Mnew = out + (size_t)BH * S * D;
    float* znew = Mnew + (size_t)BH * D * D;

    // Scratch in the front of `out` (fully overwritten by k_retrieve later;
    // stream-ordered so k_sum/k_gm read it first).
    float* pP   = out;
    float* pG   = pP + (size_t)NCH * BH * D * D;
    float* pz   = pG + (size_t)NCH * BH * D * D;
    float* Mtmp = pz + (size_t)NCH * BH * D;
    ushort_t* gh = (ushort_t*)(Mtmp + (size_t)BH * D * D);
    ushort_t* gl = gh + (size_t)BH * D * D;

    dim3 gridA(BH, NCH);
    k_update<<<gridA, 512, 0, stream>>>(k, v, z, pP, pG, pz, S);
    dim3 gridB(BH, 8);
    k_sum<<<gridB, 256, 0, stream>>>(M, z, pP, pG, pz, Mtmp, gh, gl, znew, NCH);
    k_gm<<<BH, 256, 0, stream>>>(M, Mtmp, gh, gl, Mnew);
    dim3 gridC(BH, 8);
    k_retrieve<<<gridC, 256, 0, stream>>>(q, Mnew, znew, out, S);
}